// Round 1
// baseline (995.260 us; speedup 1.0000x reference)
//
#include <hip/hip_runtime.h>
#include <math.h>

#define D      512
#define BQ     128     // batch B
#define KK     3
#define THR    0.15f
#define SSCALE 5.0f

#define BN  128        // columns (img rows) per block
#define KC  32         // K-chunk
#define LDA 132        // padded LDS stride for A/B chunks (floats)
#define LDC 129        // padded LDS stride for C tile (floats) -> conflict-free row scan

// ---------------- kernel 1: normalize i_feats rows ----------------
__global__ void norm_rows_kernel(const float* __restrict__ x, float* __restrict__ xh) {
    int r = blockIdx.x;
    int l = threadIdx.x;             // 0..63
    const float4* row = (const float4*)(x + (size_t)r * D);
    float4 v0 = row[l * 2 + 0];
    float4 v1 = row[l * 2 + 1];
    float s = v0.x*v0.x + v0.y*v0.y + v0.z*v0.z + v0.w*v0.w
            + v1.x*v1.x + v1.y*v1.y + v1.z*v1.z + v1.w*v1.w;
    #pragma unroll
    for (int off = 32; off > 0; off >>= 1) s += __shfl_xor(s, off);
    float inv = 1.0f / sqrtf(s);
    float4* orow = (float4*)(xh + (size_t)r * D);
    orow[l*2+0] = make_float4(v0.x*inv, v0.y*inv, v0.z*inv, v0.w*inv);
    orow[l*2+1] = make_float4(v1.x*inv, v1.y*inv, v1.z*inv, v1.w*inv);
}

// tie-aware top-4 insert: matches jax.lax.top_k (descending, lower index wins ties)
__device__ __forceinline__ void ins4(float v, int c,
                                     float& v0, float& v1, float& v2, float& v3,
                                     int& c0, int& c1, int& c2, int& c3) {
    bool b0 = (v > v0) || (v == v0 && c < c0);
    bool b1 = (v > v1) || (v == v1 && c < c1);
    bool b2 = (v > v2) || (v == v2 && c < c2);
    bool b3 = (v > v3) || (v == v3 && c < c3);
    if (b0)      { v3=v2; c3=c2; v2=v1; c2=c1; v1=v0; c1=c0; v0=v; c0=c; }
    else if (b1) { v3=v2; c3=c2; v2=v1; c2=c1; v1=v;  c1=c; }
    else if (b2) { v3=v2; c3=c2; v2=v;  c2=c; }
    else if (b3) { v3=v;  c3=c; }
}

// ---------------- kernel 2: fused sim GEMM + per-block top-4 ----------------
// C[r][c] = ihat[r] . img[c] / ||img[c]||, block covers 128 rows x 128 cols.
__global__ __launch_bounds__(256)
void sim_topk_kernel(const float* __restrict__ ihat, const float* __restrict__ img,
                     int N, float* __restrict__ pv, int* __restrict__ pi)
{
    extern __shared__ float lds[];
    float* As = lds;                  // [KC][LDA] transposed A chunk
    float* Bs = lds + KC * LDA;       // [KC][LDA] transposed B chunk
    float* Cs = lds;                  // [BQ][LDC] C tile (reuses As/Bs space)

    const int tid = threadIdx.x;
    const int tx = tid & 15, ty = tid >> 4;
    const int c_base = blockIdx.x * BN;

    float acc[8][8];
    #pragma unroll
    for (int i = 0; i < 8; ++i)
        #pragma unroll
        for (int j = 0; j < 8; ++j) acc[i][j] = 0.0f;
    float sq[8] = {0,0,0,0,0,0,0,0};

    for (int kc = 0; kc < D; kc += KC) {
        // stage A and B chunks (transposed) : 128 rows x 32 k each
        #pragma unroll
        for (int it = 0; it < 4; ++it) {
            int e  = tid + it * 256;          // 0..1023
            int r  = e >> 3;
            int s4 = (e & 7) << 2;
            float4 va = *(const float4*)(ihat + (size_t)r * D + kc + s4);
            As[(s4+0)*LDA + r] = va.x;
            As[(s4+1)*LDA + r] = va.y;
            As[(s4+2)*LDA + r] = va.z;
            As[(s4+3)*LDA + r] = va.w;
            int c = c_base + r;
            float4 vb = make_float4(0.f,0.f,0.f,0.f);
            if (c < N) vb = *(const float4*)(img + (size_t)c * D + kc + s4);
            Bs[(s4+0)*LDA + r] = vb.x;
            Bs[(s4+1)*LDA + r] = vb.y;
            Bs[(s4+2)*LDA + r] = vb.z;
            Bs[(s4+3)*LDA + r] = vb.w;
        }
        __syncthreads();
        #pragma unroll 4
        for (int k = 0; k < KC; ++k) {
            float4 a0 = *(const float4*)(As + k*LDA + ty*8);
            float4 a1 = *(const float4*)(As + k*LDA + ty*8 + 4);
            float4 b0 = *(const float4*)(Bs + k*LDA + tx*8);
            float4 b1 = *(const float4*)(Bs + k*LDA + tx*8 + 4);
            float a[8] = {a0.x,a0.y,a0.z,a0.w,a1.x,a1.y,a1.z,a1.w};
            float b[8] = {b0.x,b0.y,b0.z,b0.w,b1.x,b1.y,b1.z,b1.w};
            #pragma unroll
            for (int j = 0; j < 8; ++j) sq[j] = fmaf(b[j], b[j], sq[j]);
            #pragma unroll
            for (int i = 0; i < 8; ++i)
                #pragma unroll
                for (int j = 0; j < 8; ++j) acc[i][j] = fmaf(a[i], b[j], acc[i][j]);
        }
        __syncthreads();
    }

    float invn[8];
    #pragma unroll
    for (int j = 0; j < 8; ++j) invn[j] = (sq[j] > 0.0f) ? 1.0f / sqrtf(sq[j]) : 0.0f;

    // write normalized C tile to LDS (As/Bs dead now; last sync was after final k-loop)
    #pragma unroll
    for (int i = 0; i < 8; ++i)
        #pragma unroll
        for (int j = 0; j < 8; ++j)
            Cs[(ty*8+i)*LDC + (tx*8+j)] = acc[i][j] * invn[j];
    __syncthreads();

    if (tid < BQ) {
        float v0=-1e30f, v1=-1e30f, v2=-1e30f, v3=-1e30f;
        int   c0=0x7fffffff, c1=0x7fffffff, c2=0x7fffffff, c3=0x7fffffff;
        const float* crow = Cs + tid * LDC;
        for (int j = 0; j < BN; ++j) {
            int c = c_base + j;
            if (c >= N) break;
            ins4(crow[j], c, v0,v1,v2,v3, c0,c1,c2,c3);
        }
        int base = blockIdx.x * (BQ * 4) + tid * 4;
        pv[base+0] = v0; pv[base+1] = v1; pv[base+2] = v2; pv[base+3] = v3;
        pi[base+0] = c0; pi[base+1] = c1; pi[base+2] = c2; pi[base+3] = c3;
    }
}

// ---------------- kernel 3: reduce partials -> top-4 -> weights ----------------
__global__ void topk_reduce_kernel(const float* __restrict__ pv, const int* __restrict__ pi,
                                   int nb, float* __restrict__ swo,
                                   int* __restrict__ sidxo, int* __restrict__ valido)
{
    __shared__ float lv[256 * 4];
    __shared__ int   li[256 * 4];
    const int r = blockIdx.x, tid = threadIdx.x;

    float v0=-1e30f, v1=-1e30f, v2=-1e30f, v3=-1e30f;
    int   c0=0x7fffffff, c1=0x7fffffff, c2=0x7fffffff, c3=0x7fffffff;
    for (int blk = tid; blk < nb; blk += 256) {
        int base = blk * (BQ * 4) + r * 4;
        #pragma unroll
        for (int s = 0; s < 4; ++s) {
            float v = pv[base+s]; int c = pi[base+s];
            if (c != 0x7fffffff) ins4(v, c, v0,v1,v2,v3, c0,c1,c2,c3);
        }
    }
    lv[tid*4+0]=v0; lv[tid*4+1]=v1; lv[tid*4+2]=v2; lv[tid*4+3]=v3;
    li[tid*4+0]=c0; li[tid*4+1]=c1; li[tid*4+2]=c2; li[tid*4+3]=c3;
    __syncthreads();
    if (tid < 16) {
        for (int o = 1; o < 16; ++o) {
            int t2 = tid + o * 16;
            #pragma unroll
            for (int s = 0; s < 4; ++s)
                ins4(lv[t2*4+s], li[t2*4+s], v0,v1,v2,v3, c0,c1,c2,c3);
        }
        lv[tid*4+0]=v0; lv[tid*4+1]=v1; lv[tid*4+2]=v2; lv[tid*4+3]=v3;
        li[tid*4+0]=c0; li[tid*4+1]=c1; li[tid*4+2]=c2; li[tid*4+3]=c3;
    }
    __syncthreads();
    if (tid == 0) {
        for (int o = 1; o < 16; ++o)
            #pragma unroll
            for (int s = 0; s < 4; ++s)
                ins4(lv[o*4+s], li[o*4+s], v0,v1,v2,v3, c0,c1,c2,c3);
        // top-4 descending: (v0..v3). Drop rank0, candidates = ranks 1..3.
        float cv[3] = {v1, v2, v3};
        int   ci[3] = {c1, c2, c3};
        int   vd[3];
        float lg[4];
        lg[0] = SSCALE;
        #pragma unroll
        for (int k = 0; k < 3; ++k) {
            vd[k] = (cv[k] > THR) ? 1 : 0;
            lg[k+1] = vd[k] ? SSCALE * cv[k] : -1e30f;
        }
        float m = fmaxf(fmaxf(lg[0], lg[1]), fmaxf(lg[2], lg[3]));
        float e0 = expf(lg[0]-m), e1 = expf(lg[1]-m), e2 = expf(lg[2]-m), e3 = expf(lg[3]-m);
        float sum = e0 + e1 + e2 + e3;
        float ee[3] = {e1, e2, e3};
        #pragma unroll
        for (int k = 0; k < 3; ++k) {
            float w = 1.0f - ee[k] / sum;
            swo[r*3+k]   = vd[k] ? w : 0.0f;
            sidxo[r*3+k] = vd[k] ? ci[k] : 0;
            valido[r*3+k]= vd[k];
        }
    }
}

// ---------------- kernel 4: assemble output (1536 x 512 fp32) ----------------
__global__ void assemble_kernel(const float* __restrict__ i_feats, const float* __restrict__ t_feats,
                                const float* __restrict__ img, const float* __restrict__ txt,
                                const float* __restrict__ sw, const int* __restrict__ sidx,
                                const int* __restrict__ valid, float* __restrict__ out)
{
    const int r = blockIdx.x;      // 0..1535
    const int t = threadIdx.x;     // 0..127 (float4 per thread)
    float4* orow = (float4*)(out + (size_t)r * D);
    if (r < 128) {
        orow[t] = ((const float4*)(i_feats + (size_t)r * D))[t];
    } else if (r < 512) {
        int s = r - 128;
        float4 v = make_float4(0.f,0.f,0.f,0.f);
        if (valid[s]) v = ((const float4*)(img + (size_t)sidx[s] * D))[t];
        orow[t] = v;
    } else if (r < 640) {
        orow[t] = ((const float4*)(t_feats + (size_t)(r - 512) * D))[t];
    } else if (r < 1024) {
        int s = r - 640;
        float4 v = make_float4(0.f,0.f,0.f,0.f);
        if (valid[s]) v = ((const float4*)(txt + (size_t)sidx[s] * D))[t];
        orow[t] = v;
    } else {
        int li = r - 1024;         // label row 0..511
        float o[4];
        int j0 = t * 4;
        if (li < 128) {
            #pragma unroll
            for (int u = 0; u < 4; ++u) {
                int j = j0 + u;
                if (j < 128) o[u] = (j == li) ? 1.0f : 0.0f;
                else {
                    int s = j - 128;
                    o[u] = (s / 3 == li) ? sw[li*3 + (s % 3)] : 0.0f;
                }
            }
        } else {
            int i2 = li - 128;
            int b = i2 / 3;
            int vi = valid[i2];
            #pragma unroll
            for (int u = 0; u < 4; ++u) {
                int j = j0 + u;
                float val;
                if (j < 128) val = (vi && j == b) ? 1.0f : 0.0f;
                else {
                    int s2 = j - 128;
                    int vj = valid[s2];
                    int b2 = s2 / 3;
                    if (vi && vj)        val = (b == b2) ? 1.0f : 0.0f;
                    else if (!vi && !vj) val = (i2 == s2) ? 1.0f : 0.0f;
                    else                 val = 0.0f;
                }
                o[u] = val;
            }
        }
        orow[t] = make_float4(o[0], o[1], o[2], o[3]);
    }
}

extern "C" void kernel_launch(void* const* d_in, const int* in_sizes, int n_in,
                              void* d_out, int out_size, void* d_ws, size_t ws_size,
                              hipStream_t stream) {
    const float* i_feats = (const float*)d_in[0];
    const float* t_feats = (const float*)d_in[1];
    const float* img     = (const float*)d_in[2];
    const float* txt     = (const float*)d_in[3];
    float* out = (float*)d_out;

    const int N  = in_sizes[2] / D;            // 200000
    const int nb = (N + BN - 1) / BN;          // 1563

    // workspace layout (~6.7 MB)
    char* ws = (char*)d_ws;
    float* ihat = (float*)ws;                        size_t off = (size_t)BQ * D * 4;
    float* pv   = (float*)(ws + off);                off += (size_t)nb * BQ * 4 * 4;
    int*   pi   = (int*)(ws + off);                  off += (size_t)nb * BQ * 4 * 4;
    float* swv  = (float*)(ws + off);                off += BQ * 3 * 4;
    int*   sidx = (int*)(ws + off);                  off += BQ * 3 * 4;
    int*   vld  = (int*)(ws + off);

    norm_rows_kernel<<<BQ, 64, 0, stream>>>(i_feats, ihat);
    sim_topk_kernel<<<nb, 256, BQ * LDC * 4, stream>>>(ihat, img, N, pv, pi);
    topk_reduce_kernel<<<BQ, 256, 0, stream>>>(pv, pi, nb, swv, sidx, vld);
    assemble_kernel<<<3 * (BQ + BQ * KK), 128, 0, stream>>>(i_feats, t_feats, img, txt,
                                                            swv, sidx, vld, out);
}

// Round 2
// 735.595 us; speedup vs baseline: 1.3530x; 1.3530x over previous
//
#include <hip/hip_runtime.h>
#include <math.h>

#define D      512
#define BQ     128
#define KK     3
#define THR    0.15f
#define SSCALE 5.0f
#define BN     128
#define KC     64
#define NCH    8          // D / KC
#define SENT   0x7fffffff

using bf16x8 = __attribute__((ext_vector_type(8))) short;
using f32x4  = __attribute__((ext_vector_type(4))) float;

__device__ __forceinline__ unsigned short f2bf(float x) {
    unsigned u = __float_as_uint(x);
    return (unsigned short)((u + 0x7fffu + ((u >> 16) & 1u)) >> 16);
}

// tie-aware top-4 insert (descending, lower index wins ties) — matches jax.lax.top_k
__device__ __forceinline__ void ins4(float v, int c,
                                     float& v0, float& v1, float& v2, float& v3,
                                     int& c0, int& c1, int& c2, int& c3) {
    bool b0 = (v > v0) || (v == v0 && c < c0);
    bool b1 = (v > v1) || (v == v1 && c < c1);
    bool b2 = (v > v2) || (v == v2 && c < c2);
    bool b3 = (v > v3) || (v == v3 && c < c3);
    if (b0)      { v3=v2; c3=c2; v2=v1; c2=c1; v1=v0; c1=c0; v0=v; c0=c; }
    else if (b1) { v3=v2; c3=c2; v2=v1; c2=c1; v1=v;  c1=c; }
    else if (b2) { v3=v2; c3=c2; v2=v;  c2=c; }
    else if (b3) { v3=v;  c3=c; }
}

template<int K>
__device__ __forceinline__ void insK(float v, int c, float* V, int* C) {
    #pragma unroll
    for (int k = 0; k < K; ++k) {
        if (v > V[k] || (v == V[k] && c < C[k])) {
            #pragma unroll
            for (int m = K - 1; m > k; --m) { V[m] = V[m-1]; C[m] = C[m-1]; }
            V[k] = v; C[k] = c;
            return;
        }
    }
}

// ---------------- kernel 1: normalize i_feats rows (fp32, exact) ----------------
__global__ void norm_rows_kernel(const float* __restrict__ x, float* __restrict__ xh) {
    int r = blockIdx.x;
    int l = threadIdx.x;             // 0..63
    const float4* row = (const float4*)(x + (size_t)r * D);
    float4 v0 = row[l * 2 + 0];
    float4 v1 = row[l * 2 + 1];
    float s = v0.x*v0.x + v0.y*v0.y + v0.z*v0.z + v0.w*v0.w
            + v1.x*v1.x + v1.y*v1.y + v1.z*v1.z + v1.w*v1.w;
    #pragma unroll
    for (int off = 32; off > 0; off >>= 1) s += __shfl_xor(s, off);
    float inv = 1.0f / sqrtf(s);
    float4* orow = (float4*)(xh + (size_t)r * D);
    orow[l*2+0] = make_float4(v0.x*inv, v0.y*inv, v0.z*inv, v0.w*inv);
    orow[l*2+1] = make_float4(v1.x*inv, v1.y*inv, v1.z*inv, v1.w*inv);
}

// ---------------- kernel 2: build pre-swizzled bf16 A image ----------------
// A image: [chunk 0..7][1024 x 16B slots]. Slot q holds bf16 elems of
// (row=q>>3, kbytes = ((q&7)<<4) ^ ((row&7)<<4)) so that a LINEAR LDS copy
// yields the XOR-swizzled tile the frag reads expect.
__global__ void apre_kernel(const float* __restrict__ ihat, uint4* __restrict__ apre) {
    int s = blockIdx.x * 256 + threadIdx.x;   // 0..8191
    int chunk = s >> 10;
    int q = s & 1023;
    int row = q >> 3;
    int inner = (q & 7) << 4;
    int unsw = inner ^ ((row & 7) << 4);
    int k = chunk * KC + (unsw >> 1);
    const float* src = ihat + row * D + k;
    float4 f0 = *(const float4*)(src);
    float4 f1 = *(const float4*)(src + 4);
    uint4 p;
    p.x = f2bf(f0.x) | ((unsigned)f2bf(f0.y) << 16);
    p.y = f2bf(f0.z) | ((unsigned)f2bf(f0.w) << 16);
    p.z = f2bf(f1.x) | ((unsigned)f2bf(f1.y) << 16);
    p.w = f2bf(f1.z) | ((unsigned)f2bf(f1.w) << 16);
    apre[s] = p;
}

// ---------------- kernel 3: MFMA sim + per-block top-4 ----------------
// LDS: bufA0 @0 (16K) | bufB0 @16K | bufA1 @32K | bufB1 @48K | sums @64K (512B)
// C tile (bf16 [128][136]) reuses 0..34816 after the K loop.
__global__ __launch_bounds__(256, 2)
void sim_topk_kernel(const uint4* __restrict__ apre, const float* __restrict__ img,
                     int N, float* __restrict__ pv, int* __restrict__ pi)
{
    extern __shared__ __align__(16) unsigned char lds[];
    const int tid  = threadIdx.x;
    const int lane = tid & 63;
    const int wid  = tid >> 6;

    // staging map: pair g2 = i*256+tid -> row = i*32 + (tid>>3), slot-pair = tid&7
    const int row_t = tid >> 3;
    const int sp    = tid & 7;
    int wb[4];
    #pragma unroll
    for (int i = 0; i < 4; ++i) {
        int r = i * 32 + row_t;
        wb[i] = ((r * 128) | (sp * 16)) ^ ((row_t & 7) << 4);
    }

    // frag LDS offsets (swizzled): row-major [128][64] bf16, 128B rows
    int a_off[2], b_off[8];
    {
        int lr = lane & 15, kg = lane >> 4;
        #pragma unroll
        for (int mf = 0; mf < 2; ++mf) {
            int r = wid * 32 + mf * 16 + lr;
            a_off[mf] = ((r * 128) | (kg * 16)) ^ ((r & 7) << 4);
        }
        #pragma unroll
        for (int nf = 0; nf < 8; ++nf) {
            int r = nf * 16 + lr;
            b_off[nf] = ((r * 128) | (kg * 16)) ^ ((r & 7) << 4);
        }
    }

    // persistent per-row top-4 (across both column tiles)
    float v0=-1e30f, v1=-1e30f, v2=-1e30f, v3=-1e30f;
    int   c0=SENT, c1=SENT, c2=SENT, c3=SENT;

    for (int tile = 0; tile < 2; ++tile) {
        int tb = blockIdx.x + tile * gridDim.x;
        if (tb * BN >= N) break;
        const int c_base = tb * BN;

        size_t gB[4]; bool gok[4];
        #pragma unroll
        for (int i = 0; i < 4; ++i) {
            int gc = c_base + i * 32 + row_t;
            gok[i] = gc < N;
            gB[i]  = (size_t)(gok[i] ? gc : 0) * D + sp * 8;
        }

        f32x4 acc[2][8];
        #pragma unroll
        for (int m = 0; m < 2; ++m)
            #pragma unroll
            for (int n = 0; n < 8; ++n) acc[m][n] = (f32x4){0.f,0.f,0.f,0.f};
        float sq[4] = {0.f, 0.f, 0.f, 0.f};

        float4 rB[4][2];
        uint4  rA[4];

        auto loadChunk = [&](int c) {
            int kc = c * KC;
            #pragma unroll
            for (int i = 0; i < 4; ++i) {
                const float* s = img + gB[i] + kc;
                if (gok[i]) {
                    rB[i][0] = *(const float4*)(s);
                    rB[i][1] = *(const float4*)(s + 4);
                } else {
                    rB[i][0] = make_float4(0.f,0.f,0.f,0.f);
                    rB[i][1] = make_float4(0.f,0.f,0.f,0.f);
                }
            }
            #pragma unroll
            for (int j = 0; j < 4; ++j)
                rA[j] = apre[c * 1024 + tid + j * 256];
        };

        auto procChunk = [&](int buf) {
            unsigned char* bA = lds + (buf ? 32768 : 0);
            unsigned char* bB = lds + (buf ? 49152 : 16384);
            #pragma unroll
            for (int j = 0; j < 4; ++j)
                *(uint4*)(bA + (tid + j * 256) * 16) = rA[j];
            #pragma unroll
            for (int i = 0; i < 4; ++i) {
                float4 u = rB[i][0], w = rB[i][1];
                float s = u.x*u.x + u.y*u.y + u.z*u.z + u.w*u.w
                        + w.x*w.x + w.y*w.y + w.z*w.z + w.w*w.w;
                s += __shfl_xor(s, 1);
                s += __shfl_xor(s, 2);
                s += __shfl_xor(s, 4);
                sq[i] += s;
                uint4 p;
                p.x = f2bf(u.x) | ((unsigned)f2bf(u.y) << 16);
                p.y = f2bf(u.z) | ((unsigned)f2bf(u.w) << 16);
                p.z = f2bf(w.x) | ((unsigned)f2bf(w.y) << 16);
                p.w = f2bf(w.z) | ((unsigned)f2bf(w.w) << 16);
                *(uint4*)(bB + wb[i]) = p;
            }
        };

        loadChunk(0);
        procChunk(0);
        __syncthreads();

        int cur = 0;
        for (int c = 0; c < NCH; ++c) {
            bool pf = (c + 1 < NCH);
            if (pf) loadChunk(c + 1);
            unsigned char* bA = lds + (cur ? 32768 : 0);
            unsigned char* bB = lds + (cur ? 49152 : 16384);
            #pragma unroll
            for (int ks = 0; ks < 2; ++ks) {
                int kx = ks << 6;
                bf16x8 a0 = *(const bf16x8*)(bA + (a_off[0] ^ kx));
                bf16x8 a1 = *(const bf16x8*)(bA + (a_off[1] ^ kx));
                #pragma unroll
                for (int nf = 0; nf < 8; ++nf) {
                    bf16x8 b = *(const bf16x8*)(bB + (b_off[nf] ^ kx));
                    acc[0][nf] = __builtin_amdgcn_mfma_f32_16x16x32_bf16(a0, b, acc[0][nf], 0, 0, 0);
                    acc[1][nf] = __builtin_amdgcn_mfma_f32_16x16x32_bf16(a1, b, acc[1][nf], 0, 0, 0);
                }
            }
            if (pf) procChunk(cur ^ 1);
            __syncthreads();
            cur ^= 1;
        }

        // sumsq per B-row -> LDS
        float* sums = (float*)(lds + 65536);
        if ((tid & 7) == 0) {
            #pragma unroll
            for (int i = 0; i < 4; ++i)
                sums[i * 32 + row_t] = sq[i];
        }
        __syncthreads();

        // normalized C tile (bf16) to LDS
        unsigned short* Ct = (unsigned short*)lds;
        const int LDC2 = 136;
        {
            int lr = lane & 15, rq = (lane >> 4) * 4;
            float invn[8];
            #pragma unroll
            for (int nf = 0; nf < 8; ++nf) {
                float ss = sums[nf * 16 + lr];
                invn[nf] = ss > 0.f ? rsqrtf(ss) : 0.f;
            }
            #pragma unroll
            for (int nf = 0; nf < 8; ++nf) {
                int col = nf * 16 + lr;
                #pragma unroll
                for (int mf = 0; mf < 2; ++mf) {
                    int rbase = wid * 32 + mf * 16 + rq;
                    #pragma unroll
                    for (int r = 0; r < 4; ++r)
                        Ct[(rbase + r) * LDC2 + col] = f2bf(acc[mf][nf][r] * invn[nf]);
                }
            }
        }
        __syncthreads();

        // per-row scan (2 threads/row, 64 cols each)
        {
            int row = tid >> 1, hh = tid & 1;
            int lim = N - c_base;
            const unsigned short* crow = Ct + row * LDC2 + hh * 64;
            #pragma unroll
            for (int jb = 0; jb < 8; ++jb) {
                uint4 q = *(const uint4*)(crow + jb * 8);
                unsigned wv[4] = {q.x, q.y, q.z, q.w};
                #pragma unroll
                for (int e = 0; e < 4; ++e) {
                    int cc = hh * 64 + jb * 8 + e * 2;
                    float f0 = __uint_as_float(wv[e] << 16);
                    float f1 = __uint_as_float(wv[e] & 0xffff0000u);
                    if (cc < lim)     ins4(f0, c_base + cc,     v0,v1,v2,v3, c0,c1,c2,c3);
                    if (cc + 1 < lim) ins4(f1, c_base + cc + 1, v0,v1,v2,v3, c0,c1,c2,c3);
                }
            }
        }
        __syncthreads();   // Ct/sums reused by next tile's staging
    }

    // merge with partner thread (other half of the row), write block top-4
    {
        int row = tid >> 1;
        float mv; int mc;
        mv = __shfl_xor(v0, 1); mc = __shfl_xor(c0, 1); ins4(mv, mc, v0,v1,v2,v3, c0,c1,c2,c3);
        mv = __shfl_xor(v1, 1); mc = __shfl_xor(c1, 1); ins4(mv, mc, v0,v1,v2,v3, c0,c1,c2,c3);
        mv = __shfl_xor(v2, 1); mc = __shfl_xor(c2, 1); ins4(mv, mc, v0,v1,v2,v3, c0,c1,c2,c3);
        mv = __shfl_xor(v3, 1); mc = __shfl_xor(c3, 1); ins4(mv, mc, v0,v1,v2,v3, c0,c1,c2,c3);
        if ((tid & 1) == 0) {
            size_t base = (size_t)blockIdx.x * (BQ * 4) + row * 4;
            pv[base+0] = v0; pv[base+1] = v1; pv[base+2] = v2; pv[base+3] = v3;
            pi[base+0] = c0; pi[base+1] = c1; pi[base+2] = c2; pi[base+3] = c3;
        }
    }
}

// ---------------- kernel 4: reduce partials -> global top-8 per row ----------------
__global__ void topk_reduce8(const float* __restrict__ pv, const int* __restrict__ pi,
                             int nb, float* __restrict__ gv, int* __restrict__ gi)
{
    __shared__ float lv[256][8];
    __shared__ int   li[256][8];
    const int r = blockIdx.x, tid = threadIdx.x;
    float V[8]; int C[8];
    #pragma unroll
    for (int k = 0; k < 8; ++k) { V[k] = -1e30f; C[k] = SENT; }
    for (int b = tid; b < nb; b += 256) {
        size_t base = (size_t)b * (BQ * 4) + r * 4;
        #pragma unroll
        for (int s = 0; s < 4; ++s) {
            int c = pi[base + s];
            if (c != SENT) insK<8>(pv[base + s], c, V, C);
        }
    }
    #pragma unroll
    for (int k = 0; k < 8; ++k) { lv[tid][k] = V[k]; li[tid][k] = C[k]; }
    __syncthreads();
    if (tid < 16) {
        for (int o = 1; o < 16; ++o) {
            int t2 = tid + o * 16;
            #pragma unroll
            for (int s = 0; s < 8; ++s)
                if (li[t2][s] != SENT) insK<8>(lv[t2][s], li[t2][s], V, C);
        }
        #pragma unroll
        for (int k = 0; k < 8; ++k) { lv[tid][k] = V[k]; li[tid][k] = C[k]; }
    }
    __syncthreads();
    if (tid == 0) {
        for (int o = 1; o < 16; ++o)
            #pragma unroll
            for (int s = 0; s < 8; ++s)
                if (li[o][s] != SENT) insK<8>(lv[o][s], li[o][s], V, C);
        #pragma unroll
        for (int k = 0; k < 8; ++k) { gv[r*8+k] = V[k]; gi[r*8+k] = C[k]; }
    }
}

// ---------------- kernel 5: exact fp32 rescore of 8 candidates -> weights ----------------
__global__ void rescore_kernel(const float* __restrict__ ihat, const float* __restrict__ img,
                               const int* __restrict__ gi,
                               float* __restrict__ swo, int* __restrict__ sidxo,
                               int* __restrict__ valido)
{
    __shared__ float sv[8];
    __shared__ int   si[8];
    const int r = blockIdx.x, tid = threadIdx.x;
    const int k = tid >> 5, l = tid & 31;
    int idx = gi[r*8 + k];
    float dot = 0.f, ssq = 0.f;
    if (idx != SENT) {
        const float* a = ihat + r * D + l * 16;
        const float* b = img + (size_t)idx * D + l * 16;
        #pragma unroll
        for (int j = 0; j < 4; ++j) {
            float4 va = *(const float4*)(a + j*4);
            float4 vb = *(const float4*)(b + j*4);
            dot += va.x*vb.x + va.y*vb.y + va.z*vb.z + va.w*vb.w;
            ssq += vb.x*vb.x + vb.y*vb.y + vb.z*vb.z + vb.w*vb.w;
        }
    }
    #pragma unroll
    for (int o = 16; o > 0; o >>= 1) { dot += __shfl_xor(dot, o); ssq += __shfl_xor(ssq, o); }
    if (l == 0) {
        sv[k] = (idx != SENT && ssq > 0.f) ? dot * rsqrtf(ssq) : -1e30f;
        si[k] = idx;
    }
    __syncthreads();
    if (tid == 0) {
        float V[4]; int C[4];
        #pragma unroll
        for (int k2 = 0; k2 < 4; ++k2) { V[k2] = -1e30f; C[k2] = SENT; }
        #pragma unroll
        for (int k2 = 0; k2 < 8; ++k2)
            if (si[k2] != SENT) insK<4>(sv[k2], si[k2], V, C);
        float lg[4]; int vd[3];
        lg[0] = SSCALE;
        #pragma unroll
        for (int k2 = 0; k2 < 3; ++k2) {
            vd[k2] = (V[k2+1] > THR) ? 1 : 0;
            lg[k2+1] = vd[k2] ? SSCALE * V[k2+1] : -1e30f;
        }
        float m = fmaxf(fmaxf(lg[0], lg[1]), fmaxf(lg[2], lg[3]));
        float e0 = expf(lg[0]-m), e1 = expf(lg[1]-m), e2 = expf(lg[2]-m), e3 = expf(lg[3]-m);
        float sum = e0 + e1 + e2 + e3;
        float ee[3] = {e1, e2, e3};
        #pragma unroll
        for (int k2 = 0; k2 < 3; ++k2) {
            float w = 1.0f - ee[k2] / sum;
            swo[r*3+k2]    = vd[k2] ? w : 0.0f;
            sidxo[r*3+k2]  = vd[k2] ? C[k2+1] : 0;
            valido[r*3+k2] = vd[k2];
        }
    }
}

// ---------------- kernel 6: assemble output (1536 x 512 fp32) ----------------
__global__ void assemble_kernel(const float* __restrict__ i_feats, const float* __restrict__ t_feats,
                                const float* __restrict__ img, const float* __restrict__ txt,
                                const float* __restrict__ sw, const int* __restrict__ sidx,
                                const int* __restrict__ valid, float* __restrict__ out)
{
    const int r = blockIdx.x;      // 0..1535
    const int t = threadIdx.x;     // 0..127
    float4* orow = (float4*)(out + (size_t)r * D);
    if (r < 128) {
        orow[t] = ((const float4*)(i_feats + (size_t)r * D))[t];
    } else if (r < 512) {
        int s = r - 128;
        float4 v = make_float4(0.f,0.f,0.f,0.f);
        if (valid[s]) v = ((const float4*)(img + (size_t)sidx[s] * D))[t];
        orow[t] = v;
    } else if (r < 640) {
        orow[t] = ((const float4*)(t_feats + (size_t)(r - 512) * D))[t];
    } else if (r < 1024) {
        int s = r - 640;
        float4 v = make_float4(0.f,0.f,0.f,0.f);
        if (valid[s]) v = ((const float4*)(txt + (size_t)sidx[s] * D))[t];
        orow[t] = v;
    } else {
        int li = r - 1024;
        float o[4];
        int j0 = t * 4;
        if (li < 128) {
            #pragma unroll
            for (int u = 0; u < 4; ++u) {
                int j = j0 + u;
                if (j < 128) o[u] = (j == li) ? 1.0f : 0.0f;
                else {
                    int s = j - 128;
                    o[u] = (s / 3 == li) ? sw[li*3 + (s % 3)] : 0.0f;
                }
            }
        } else {
            int i2 = li - 128;
            int b = i2 / 3;
            int vi = valid[i2];
            #pragma unroll
            for (int u = 0; u < 4; ++u) {
                int j = j0 + u;
                float val;
                if (j < 128) val = (vi && j == b) ? 1.0f : 0.0f;
                else {
                    int s2 = j - 128;
                    int vj = valid[s2];
                    int b2 = s2 / 3;
                    if (vi && vj)        val = (b == b2) ? 1.0f : 0.0f;
                    else if (!vi && !vj) val = (i2 == s2) ? 1.0f : 0.0f;
                    else                 val = 0.0f;
                }
                o[u] = val;
            }
        }
        orow[t] = make_float4(o[0], o[1], o[2], o[3]);
    }
}

extern "C" void kernel_launch(void* const* d_in, const int* in_sizes, int n_in,
                              void* d_out, int out_size, void* d_ws, size_t ws_size,
                              hipStream_t stream) {
    const float* i_feats = (const float*)d_in[0];
    const float* t_feats = (const float*)d_in[1];
    const float* img     = (const float*)d_in[2];
    const float* txt     = (const float*)d_in[3];
    float* out = (float*)d_out;

    const int N   = in_sizes[2] / D;           // 200000
    const int nb  = (N + BN - 1) / BN;         // 1563
    const int nbh = (nb + 1) / 2;              // 782 blocks, 2 tiles each

    char* ws = (char*)d_ws;
    size_t off = 0;
    float* ihat = (float*)(ws + off); off += (size_t)BQ * D * 4;      // 256 KB
    uint4* apre = (uint4*)(ws + off); off += (size_t)BQ * D * 2;      // 128 KB
    float* pv   = (float*)(ws + off); off += (size_t)nbh * BQ * 4 * 4;
    int*   pi   = (int*)(ws + off);   off += (size_t)nbh * BQ * 4 * 4;
    float* gv   = (float*)(ws + off); off += BQ * 8 * 4;
    int*   gi   = (int*)(ws + off);   off += BQ * 8 * 4;
    float* swv  = (float*)(ws + off); off += BQ * 4 * 4;
    int*   sidx = (int*)(ws + off);   off += BQ * 4 * 4;
    int*   vld  = (int*)(ws + off);   off += BQ * 4 * 4;

    norm_rows_kernel<<<BQ, 64, 0, stream>>>(i_feats, ihat);
    apre_kernel<<<32, 256, 0, stream>>>(ihat, apre);
    sim_topk_kernel<<<nbh, 256, 66048, stream>>>(apre, img, N, pv, pi);
    topk_reduce8<<<BQ, 256, 0, stream>>>(pv, pi, nbh, gv, gi);
    rescore_kernel<<<BQ, 256, 0, stream>>>(ihat, img, gi, swv, sidx, vld);
    assemble_kernel<<<3 * (BQ + BQ * KK), 128, 0, stream>>>(i_feats, t_feats, img, txt,
                                                            swv, sidx, vld, out);
}